// Round 6
// baseline (316.877 us; speedup 1.0000x reference)
//
#include <hip/hip_runtime.h>
#include <hip/hip_bf16.h>

// Problem constants (BertSelfAttention_979252544303)
#define SEQ   2048
#define BATCH 2
#define HID   1024
#define NHEAD 16
#define HDIM  64
#define BH    (BATCH * NHEAD)   // 32 flattened heads

using short8   = __attribute__((ext_vector_type(8))) short;
using floatx4  = __attribute__((ext_vector_type(4))) float;

#define LOG2E 1.44269504f
#define SCALE_LOG2E (0.125f * LOG2E)   // (1/sqrt(64)) * log2(e)

// float -> bf16 (RNE)
static __device__ __forceinline__ unsigned short f2bf(float f) {
    unsigned int u = __builtin_bit_cast(unsigned int, f);
    u += 0x7fffu + ((u >> 16) & 1u);
    return (unsigned short)(u >> 16);
}

#define GLD16(gp, lp)                                                        \
    __builtin_amdgcn_global_load_lds(                                        \
        (const __attribute__((address_space(1))) void*)(gp),                 \
        (__attribute__((address_space(3))) void*)(lp), 16, 0, 0)

// ---------------------------------------------------------------------------
// Prep 1: x fp32 [4096][1024] -> bf16 (straight). 1 float4 per thread.
// ---------------------------------------------------------------------------
__global__ __launch_bounds__(256) void convert_x(
    const float* __restrict__ x, unsigned short* __restrict__ xb)
{
    const int i = blockIdx.x * 256 + threadIdx.x;
    const float4 v = ((const float4*)x)[i];
    ushort4 o;
    o.x = f2bf(v.x); o.y = f2bf(v.y); o.z = f2bf(v.z); o.w = f2bf(v.w);
    ((ushort4*)xb)[i] = o;
}

// ---------------------------------------------------------------------------
// Prep 2: W fp32 [k][n] -> wt bf16 [n][k], tiled transpose. z selects Q/K/V.
// ---------------------------------------------------------------------------
__global__ __launch_bounds__(256) void transpose_w(
    const float* __restrict__ Wq, const float* __restrict__ Wk,
    const float* __restrict__ Wv, unsigned short* __restrict__ wt)
{
    const float* W = (blockIdx.z == 0) ? Wq : (blockIdx.z == 1) ? Wk : Wv;
    unsigned short* out = wt + (size_t)blockIdx.z * HID * HID;
    __shared__ float tile[32][33];
    const int tx = threadIdx.x & 31, ty = threadIdx.x >> 5;
    const int bx = blockIdx.x * 32, by = blockIdx.y * 32;
    #pragma unroll
    for (int j = 0; j < 4; ++j)
        tile[ty + j * 8][tx] = W[(size_t)(by + ty + j * 8) * HID + bx + tx];
    __syncthreads();
    #pragma unroll
    for (int j = 0; j < 4; ++j)
        out[(size_t)(bx + ty + j * 8) * HID + by + tx] = f2bf(tile[tx][ty + j * 8]);
}

// ---------------------------------------------------------------------------
// Kernel 1: fused QKV projection, bf16 MFMA (m97 structure). Unchanged (R2).
// z: 0=Q, 1=K (out [bh][s][d]), 2=V (out [bh][d][s]).
// ---------------------------------------------------------------------------
__global__ __launch_bounds__(256) void qkv_mfma(
    const unsigned short* __restrict__ xb,
    const unsigned short* __restrict__ wt,
    const float* __restrict__ bq, const float* __restrict__ bk,
    const float* __restrict__ bv,
    unsigned short* __restrict__ ws_out)
{
    const int bn = blockIdx.x;   // 0..7
    const int bm = blockIdx.y;   // 0..31
    const int z  = blockIdx.z;   // 0..2
    const unsigned short* Bt = wt + (size_t)z * HID * HID;
    const float* bias = (z == 0) ? bq : (z == 1) ? bk : bv;
    unsigned short* out = ws_out + (size_t)z * (size_t)BH * SEQ * HDIM;

    const int t    = threadIdx.x;
    const int wave = t >> 6;
    const int lane = t & 63;
    const int l15  = lane & 15;
    const int quad = lane >> 4;
    const int wm   = (wave >> 1) * 64;
    const int wn   = (wave & 1) * 64;

    __shared__ __align__(16) unsigned short As[128 * 32];
    __shared__ __align__(16) unsigned short Bs[128 * 32];

    floatx4 acc[4][4];
    #pragma unroll
    for (int i = 0; i < 4; ++i)
        #pragma unroll
        for (int j = 0; j < 4; ++j)
            acc[i][j] = (floatx4){0.f, 0.f, 0.f, 0.f};

    const int lrow = lane >> 2;
    const int lcol = (lane & 3) * 8;

    for (int kt = 0; kt < HID / 32; ++kt) {
        __syncthreads();
        #pragma unroll
        for (int ee = 0; ee < 2; ++ee) {
            const int e = wave * 2 + ee;
            const unsigned short* ga =
                xb + (size_t)(bm * 128 + e * 16 + lrow) * HID + kt * 32 + lcol;
            const unsigned short* gb =
                Bt + (size_t)(bn * 128 + e * 16 + lrow) * HID + kt * 32 + lcol;
            GLD16(ga, (char*)As + e * 1024);
            GLD16(gb, (char*)Bs + e * 1024);
        }
        __syncthreads();

        short8 af[4], bf[4];
        #pragma unroll
        for (int mt = 0; mt < 4; ++mt)
            af[mt] = *(const short8*)&As[(wm + mt * 16 + l15) * 32 + quad * 8];
        #pragma unroll
        for (int nt = 0; nt < 4; ++nt)
            bf[nt] = *(const short8*)&Bs[(wn + nt * 16 + l15) * 32 + quad * 8];
        #pragma unroll
        for (int mt = 0; mt < 4; ++mt)
            #pragma unroll
            for (int nt = 0; nt < 4; ++nt)
                acc[mt][nt] = __builtin_amdgcn_mfma_f32_16x16x32_bf16(
                    af[mt], bf[nt], acc[mt][nt], 0, 0, 0);
    }

    #pragma unroll
    for (int nt = 0; nt < 4; ++nt) {
        const int n_g = bn * 128 + wn + nt * 16 + l15;
        const float bsv = bias[n_g];
        const int h = n_g >> 6;
        const int d = n_g & 63;
        #pragma unroll
        for (int mt = 0; mt < 4; ++mt) {
            #pragma unroll
            for (int r = 0; r < 4; ++r) {
                const int m_g = bm * 128 + wm + mt * 16 + quad * 4 + r;
                const int s  = m_g >> 1;
                const int bb = m_g & 1;
                const unsigned short val = f2bf(acc[mt][nt][r] + bsv);
                if (z < 2)
                    out[((size_t)(bb * NHEAD + h) * SEQ + s) * HDIM + d] = val;
                else
                    out[((size_t)(bb * NHEAD + h) * HDIM + d) * SEQ + s] = val;
            }
        }
    }
}

// ---------------------------------------------------------------------------
// Kernel 2: flash attention v5. 128 threads = 2 waves; each wave owns 32
// q-rows as TWO 16-q column-sets sharing every K-fragment read (halves LDS
// bytes per FLOP vs v4). Fixed-shift softmax (per-lane, no in-loop shfl).
// Q frags loaded straight from global to registers (no Q staging).
// Grid (32 qb, 32 heads) = 1024 blocks; LDS 27.6 KB -> 5 blocks/CU.
// q,kp: [bh][s][d] bf16; vt: [bh][d][s] bf16; mask: [B][1][S][S] fp32.
// ---------------------------------------------------------------------------
__global__ __launch_bounds__(128) void attn_v5(
    const unsigned short* __restrict__ q,
    const unsigned short* __restrict__ kp,
    const unsigned short* __restrict__ vt,
    const float* __restrict__ mask,
    float* __restrict__ out)
{
    const int qb   = blockIdx.x;   // 0..31 query tile (64 rows)
    const int n    = blockIdx.y;   // 0..31 flattened head
    const int t    = threadIdx.x;
    const int wave = t >> 6;       // 0..1
    const int lane = t & 63;
    const int l15  = lane & 15;
    const int quad = lane >> 4;
    const int bb   = n >> 4;       // batch
    const int hh   = n & 15;       // head

    // rows padded to 72 bf16 (144 B; frag reads 2-way bank aliased = free)
    __shared__ __align__(16) unsigned short Ks[64][72];   // [key][k]
    __shared__ __align__(16) unsigned short Vs[64][72];   // [d][key]
    __shared__ __align__(16) unsigned short Ps[64][72];   // [qrow][key], wave bands

    // ---- Q fragments straight from global (one-time; 16B aligned) ----
    // B-frag for 16x16x32: n-col = l15, k = quad*8 + j
    const unsigned short* qbase = q + ((size_t)n * SEQ + qb * 64) * HDIM;
    short8 Qf[2][2];
    #pragma unroll
    for (int c = 0; c < 2; ++c)
        #pragma unroll
        for (int ks = 0; ks < 2; ++ks)
            Qf[c][ks] = *(const short8*)(qbase +
                (size_t)(wave * 32 + c * 16 + l15) * HDIM + ks * 32 + quad * 8);

    floatx4 Of[2][4];
    #pragma unroll
    for (int c = 0; c < 2; ++c)
        #pragma unroll
        for (int nt = 0; nt < 4; ++nt) Of[c][nt] = (floatx4){0.f, 0.f, 0.f, 0.f};
    float lst[2] = {0.f, 0.f};

    const unsigned short* kbase = kp + (size_t)n * SEQ * HDIM;
    const unsigned short* vbase = vt + (size_t)n * HDIM * SEQ;
    const float* mrow0 = mask + ((size_t)bb * SEQ + qb * 64 + wave * 32 + l15) * SEQ;
    const float* mrow1 = mrow0 + (size_t)16 * SEQ;

    for (int kt = 0; kt < SEQ / 64; ++kt) {
        __syncthreads();   // previous K/V tile fully consumed
        {
            const unsigned short* kb = kbase + (size_t)(kt * 64) * HDIM;
            const unsigned short* vb = vbase + kt * 64;
            #pragma unroll
            for (int u = 0; u < 4; ++u) {
                const int idx = u * 128 + t;       // 0..511 8-bf16 chunks
                const int r = idx >> 3, g8 = (idx & 7) * 8;
                *(uint4*)&Ks[r][g8] = *(const uint4*)(kb + (size_t)r * HDIM + g8);
                *(uint4*)&Vs[r][g8] = *(const uint4*)(vb + (size_t)r * SEQ + g8);
            }
        }
        __syncthreads();

        // ---- S^T = K @ Q^T: one K-frag read feeds both q column-sets ----
        floatx4 Sf[4][2];
        #pragma unroll
        for (int mt = 0; mt < 4; ++mt) {
            Sf[mt][0] = (floatx4){0.f, 0.f, 0.f, 0.f};
            Sf[mt][1] = (floatx4){0.f, 0.f, 0.f, 0.f};
            #pragma unroll
            for (int ks = 0; ks < 2; ++ks) {
                short8 a = *(const short8*)&Ks[mt * 16 + l15][ks * 32 + quad * 8];
                Sf[mt][0] = __builtin_amdgcn_mfma_f32_16x16x32_bf16(
                    a, Qf[0][ks], Sf[mt][0], 0, 0, 0);
                Sf[mt][1] = __builtin_amdgcn_mfma_f32_16x16x32_bf16(
                    a, Qf[1][ks], Sf[mt][1], 0, 0, 0);
            }
        }

        // ---- fixed-shift softmax + P pack (per-lane, no cross-lane ops) ----
        #pragma unroll
        for (int c = 0; c < 2; ++c) {
            const float* mr = (c == 0 ? mrow0 : mrow1) + kt * 64;
            #pragma unroll
            for (int mt = 0; mt < 4; ++mt) {
                const float4 m4 = *(const float4*)(mr + mt * 16 + quad * 4);
                const float mv[4] = {m4.x, m4.y, m4.z, m4.w};
                float pv[4];
                #pragma unroll
                for (int r = 0; r < 4; ++r) {
                    pv[r] = exp2f(fmaf(Sf[mt][c][r], SCALE_LOG2E, mv[r] * LOG2E));
                    lst[c] += pv[r];
                }
                ushort4 pk;
                pk.x = f2bf(pv[0]); pk.y = f2bf(pv[1]);
                pk.z = f2bf(pv[2]); pk.w = f2bf(pv[3]);
                *(ushort4*)&Ps[wave * 32 + c * 16 + l15][mt * 16 + quad * 4] = pk;
            }
        }

        // ---- PV: one V-frag read feeds both q column-sets ----
        #pragma unroll
        for (int ks = 0; ks < 2; ++ks) {
            short8 a0 = *(const short8*)&Ps[wave * 32 + l15][ks * 32 + quad * 8];
            short8 a1 = *(const short8*)&Ps[wave * 32 + 16 + l15][ks * 32 + quad * 8];
            #pragma unroll
            for (int nt = 0; nt < 4; ++nt) {
                short8 b = *(const short8*)&Vs[nt * 16 + l15][ks * 32 + quad * 8];
                Of[0][nt] = __builtin_amdgcn_mfma_f32_16x16x32_bf16(a0, b, Of[0][nt], 0, 0, 0);
                Of[1][nt] = __builtin_amdgcn_mfma_f32_16x16x32_bf16(a1, b, Of[1][nt], 0, 0, 0);
            }
        }
    }

    // ---- epilogue: reduce l across quads, normalize, store ----
    #pragma unroll
    for (int c = 0; c < 2; ++c) {
        float l = lst[c];
        l += __shfl_xor(l, 16);
        l += __shfl_xor(l, 32);    // lane with l15=q now holds full row sum
        #pragma unroll
        for (int r = 0; r < 4; ++r) {
            const float lrow = __shfl(l, quad * 4 + r);
            const float inv  = 1.0f / lrow;
            const int s = qb * 64 + wave * 32 + c * 16 + quad * 4 + r;
            float* orow = out + ((size_t)s * BATCH + bb) * HID + hh * 64;
            #pragma unroll
            for (int nt = 0; nt < 4; ++nt)
                orow[nt * 16 + l15] = Of[c][nt][r] * inv;
        }
    }
}

// ---------------------------------------------------------------------------
extern "C" void kernel_launch(void* const* d_in, const int* in_sizes, int n_in,
                              void* d_out, int out_size, void* d_ws, size_t ws_size,
                              hipStream_t stream) {
    const float* x    = (const float*)d_in[0];
    const float* mask = (const float*)d_in[1];
    const float* Wq   = (const float*)d_in[2];
    const float* bq   = (const float*)d_in[3];
    const float* Wk   = (const float*)d_in[4];
    const float* bk   = (const float*)d_in[5];
    const float* Wv   = (const float*)d_in[6];
    const float* bv   = (const float*)d_in[7];
    float* out = (float*)d_out;

    const size_t per = (size_t)BH * SEQ * HDIM;   // 4,194,304 elems (8 MB bf16)
    unsigned short* qw = (unsigned short*)d_ws;   // 8 MB
    unsigned short* kw = qw + per;                // 8 MB
    unsigned short* vw = kw + per;                // 8 MB (V transposed [bh][d][s])
    unsigned short* xb = vw + per;                // 8 MB (x bf16)
    unsigned short* wt = xb + per;                // 6 MB (3x W^T bf16)

    convert_x<<<dim3(SEQ * BATCH * HID / 4 / 256), dim3(256), 0, stream>>>(x, xb);
    transpose_w<<<dim3(32, 32, 3), dim3(256), 0, stream>>>(Wq, Wk, Wv, wt);

    qkv_mfma<<<dim3(HID / 128, SEQ * BATCH / 128, 3), dim3(256), 0, stream>>>(
        xb, wt, bq, bk, bv, qw);

    attn_v5<<<dim3(SEQ / 64, BH), dim3(128), 0, stream>>>(qw, kw, vw, mask, out);
}

// Round 7
// 262.072 us; speedup vs baseline: 1.2091x; 1.2091x over previous
//
#include <hip/hip_runtime.h>
#include <hip/hip_bf16.h>

// Problem constants (BertSelfAttention_979252544303)
#define SEQ   2048
#define BATCH 2
#define HID   1024
#define NHEAD 16
#define HDIM  64
#define BH    (BATCH * NHEAD)   // 32 flattened heads

using short4v  = __attribute__((ext_vector_type(4))) short;
using short8   = __attribute__((ext_vector_type(8))) short;
using floatx4  = __attribute__((ext_vector_type(4))) float;

#define LOG2E 1.44269504f
#define SCALE_LOG2E (0.125f * LOG2E)   // (1/sqrt(64)) * log2(e)

// float -> bf16 (RNE)
static __device__ __forceinline__ unsigned short f2bf(float f) {
    unsigned int u = __builtin_bit_cast(unsigned int, f);
    u += 0x7fffu + ((u >> 16) & 1u);
    return (unsigned short)(u >> 16);
}

// D = A(16x16 bf16) * B(16x16 bf16) + C  — per-wave MFMA, K=16
static __device__ __forceinline__ floatx4 mfma16x16x16(
    short4v a, short4v b, floatx4 c) {
#if __has_builtin(__builtin_amdgcn_mfma_f32_16x16x16bf16_1k)
    return __builtin_amdgcn_mfma_f32_16x16x16bf16_1k(a, b, c, 0, 0, 0);
#else
    floatx4 d;
    asm volatile("v_mfma_f32_16x16x16_bf16 %0, %1, %2, %3"
                 : "=v"(d) : "v"(a), "v"(b), "v"(c));
    return d;
#endif
}

#define GLD16(gp, lp)                                                        \
    __builtin_amdgcn_global_load_lds(                                        \
        (const __attribute__((address_space(1))) void*)(gp),                 \
        (__attribute__((address_space(3))) void*)(lp), 16, 0, 0)

// ---------------------------------------------------------------------------
// Prep 1: x fp32 [4096][1024] -> bf16 (straight). 1 float4 per thread.
// ---------------------------------------------------------------------------
__global__ __launch_bounds__(256) void convert_x(
    const float* __restrict__ x, unsigned short* __restrict__ xb)
{
    const int i = blockIdx.x * 256 + threadIdx.x;
    const float4 v = ((const float4*)x)[i];
    ushort4 o;
    o.x = f2bf(v.x); o.y = f2bf(v.y); o.z = f2bf(v.z); o.w = f2bf(v.w);
    ((ushort4*)xb)[i] = o;
}

// ---------------------------------------------------------------------------
// Prep 2: W fp32 [k][n] -> wt bf16 [n][k], tiled transpose. z selects Q/K/V.
// ---------------------------------------------------------------------------
__global__ __launch_bounds__(256) void transpose_w(
    const float* __restrict__ Wq, const float* __restrict__ Wk,
    const float* __restrict__ Wv, unsigned short* __restrict__ wt)
{
    const float* W = (blockIdx.z == 0) ? Wq : (blockIdx.z == 1) ? Wk : Wv;
    unsigned short* out = wt + (size_t)blockIdx.z * HID * HID;
    __shared__ float tile[32][33];
    const int tx = threadIdx.x & 31, ty = threadIdx.x >> 5;
    const int bx = blockIdx.x * 32, by = blockIdx.y * 32;
    #pragma unroll
    for (int j = 0; j < 4; ++j)
        tile[ty + j * 8][tx] = W[(size_t)(by + ty + j * 8) * HID + bx + tx];
    __syncthreads();
    #pragma unroll
    for (int j = 0; j < 4; ++j)
        out[(size_t)(bx + ty + j * 8) * HID + by + tx] = f2bf(tile[tx][ty + j * 8]);
}

// ---------------------------------------------------------------------------
// Kernel 1: fused QKV projection, bf16 MFMA (m97 structure). Unchanged (R2).
// z: 0=Q, 1=K (out [bh][s][d]), 2=V (out [bh][d][s]).
// ---------------------------------------------------------------------------
__global__ __launch_bounds__(256) void qkv_mfma(
    const unsigned short* __restrict__ xb,
    const unsigned short* __restrict__ wt,
    const float* __restrict__ bq, const float* __restrict__ bk,
    const float* __restrict__ bv,
    unsigned short* __restrict__ ws_out)
{
    const int bn = blockIdx.x;   // 0..7
    const int bm = blockIdx.y;   // 0..31
    const int z  = blockIdx.z;   // 0..2
    const unsigned short* Bt = wt + (size_t)z * HID * HID;
    const float* bias = (z == 0) ? bq : (z == 1) ? bk : bv;
    unsigned short* out = ws_out + (size_t)z * (size_t)BH * SEQ * HDIM;

    const int t    = threadIdx.x;
    const int wave = t >> 6;
    const int lane = t & 63;
    const int l15  = lane & 15;
    const int quad = lane >> 4;
    const int wm   = (wave >> 1) * 64;
    const int wn   = (wave & 1) * 64;

    __shared__ __align__(16) unsigned short As[128 * 32];
    __shared__ __align__(16) unsigned short Bs[128 * 32];

    floatx4 acc[4][4];
    #pragma unroll
    for (int i = 0; i < 4; ++i)
        #pragma unroll
        for (int j = 0; j < 4; ++j)
            acc[i][j] = (floatx4){0.f, 0.f, 0.f, 0.f};

    const int lrow = lane >> 2;
    const int lcol = (lane & 3) * 8;

    for (int kt = 0; kt < HID / 32; ++kt) {
        __syncthreads();
        #pragma unroll
        for (int ee = 0; ee < 2; ++ee) {
            const int e = wave * 2 + ee;
            const unsigned short* ga =
                xb + (size_t)(bm * 128 + e * 16 + lrow) * HID + kt * 32 + lcol;
            const unsigned short* gb =
                Bt + (size_t)(bn * 128 + e * 16 + lrow) * HID + kt * 32 + lcol;
            GLD16(ga, (char*)As + e * 1024);
            GLD16(gb, (char*)Bs + e * 1024);
        }
        __syncthreads();

        short8 af[4], bf[4];
        #pragma unroll
        for (int mt = 0; mt < 4; ++mt)
            af[mt] = *(const short8*)&As[(wm + mt * 16 + l15) * 32 + quad * 8];
        #pragma unroll
        for (int nt = 0; nt < 4; ++nt)
            bf[nt] = *(const short8*)&Bs[(wn + nt * 16 + l15) * 32 + quad * 8];
        #pragma unroll
        for (int mt = 0; mt < 4; ++mt)
            #pragma unroll
            for (int nt = 0; nt < 4; ++nt)
                acc[mt][nt] = __builtin_amdgcn_mfma_f32_16x16x32_bf16(
                    af[mt], bf[nt], acc[mt][nt], 0, 0, 0);
    }

    #pragma unroll
    for (int nt = 0; nt < 4; ++nt) {
        const int n_g = bn * 128 + wn + nt * 16 + l15;
        const float bsv = bias[n_g];
        const int h = n_g >> 6;
        const int d = n_g & 63;
        #pragma unroll
        for (int mt = 0; mt < 4; ++mt) {
            #pragma unroll
            for (int r = 0; r < 4; ++r) {
                const int m_g = bm * 128 + wm + mt * 16 + quad * 4 + r;
                const int s  = m_g >> 1;
                const int bb = m_g & 1;
                const unsigned short val = f2bf(acc[mt][nt][r] + bsv);
                if (z < 2)
                    out[((size_t)(bb * NHEAD + h) * SEQ + s) * HDIM + d] = val;
                else
                    out[((size_t)(bb * NHEAD + h) * HDIM + d) * SEQ + s] = val;
            }
        }
    }
}

// ---------------------------------------------------------------------------
// Kernel 2: flash attention v6. 256 threads, 4 waves x 16 q-rows, grid
// (32 qb, 32 heads) = 1024 blocks. Fixed-shift softmax (per-lane).
// KEY TRICK: S^T's C-frag (col q=l15, rows key=quad*4+r) is exactly the
// A-frag layout of v_mfma_f32_16x16x16_bf16 (m=l15, k=quad*4+j), so
// exp(S) packs in-register into PV's A operand — NO LDS round-trip for P.
// LDS = Ks+Vs only (18.4 KB) -> 8 blocks/CU.
// q,kp: [bh][s][d] bf16; vt: [bh][d][s] bf16; mask: [B][1][S][S] fp32.
// ---------------------------------------------------------------------------
__global__ __launch_bounds__(256) void attn_v6(
    const unsigned short* __restrict__ q,
    const unsigned short* __restrict__ kp,
    const unsigned short* __restrict__ vt,
    const float* __restrict__ mask,
    float* __restrict__ out)
{
    const int qb   = blockIdx.x;   // 0..31 query tile (64 rows)
    const int n    = blockIdx.y;   // 0..31 flattened head
    const int t    = threadIdx.x;
    const int wave = t >> 6;
    const int lane = t & 63;
    const int l15  = lane & 15;
    const int quad = lane >> 4;
    const int bb   = n >> 4;       // batch
    const int hh   = n & 15;       // head

    // rows padded to 72 bf16 (144 B; b128 frag reads 2-way aliased = free)
    __shared__ __align__(16) unsigned short Ks[64][72];   // [key][k]
    __shared__ __align__(16) unsigned short Vs[64][72];   // [d][key]

    // ---- Q fragments straight from global (one-time) ----
    const unsigned short* qbase = q + ((size_t)n * SEQ + qb * 64) * HDIM;
    short8 Qf[2];
    #pragma unroll
    for (int ks = 0; ks < 2; ++ks)
        Qf[ks] = *(const short8*)(qbase +
            (size_t)(wave * 16 + l15) * HDIM + ks * 32 + quad * 8);

    floatx4 Of[4];
    #pragma unroll
    for (int nt = 0; nt < 4; ++nt) Of[nt] = (floatx4){0.f, 0.f, 0.f, 0.f};
    float lst = 0.0f;

    const unsigned short* kbase = kp + (size_t)n * SEQ * HDIM;
    const unsigned short* vbase = vt + (size_t)n * HDIM * SEQ;
    const float* mrow = mask + ((size_t)bb * SEQ + qb * 64 + wave * 16 + l15) * SEQ;

    for (int kt = 0; kt < SEQ / 64; ++kt) {
        __syncthreads();   // previous K/V tile fully consumed
        {
            const unsigned short* kb = kbase + (size_t)(kt * 64) * HDIM;
            const unsigned short* vb = vbase + kt * 64;
            int c = t, r = c >> 3, c8 = (c & 7) * 8;
            *(uint4*)&Ks[r][c8] = *(const uint4*)(kb + (size_t)r * HDIM + c8);
            *(uint4*)&Vs[r][c8] = *(const uint4*)(vb + (size_t)r * SEQ + c8);
            c = t + 256; r = c >> 3; c8 = (c & 7) * 8;
            *(uint4*)&Ks[r][c8] = *(const uint4*)(kb + (size_t)r * HDIM + c8);
            *(uint4*)&Vs[r][c8] = *(const uint4*)(vb + (size_t)r * SEQ + c8);
        }
        __syncthreads();

        // per 16-key subtile: S^T MFMA -> softmax -> in-register P -> PV
        #pragma unroll
        for (int mt = 0; mt < 4; ++mt) {
            // S^T = K(16) @ Q^T(16): A = K rows from LDS, B = Q frags (regs)
            floatx4 c = (floatx4){0.f, 0.f, 0.f, 0.f};
            #pragma unroll
            for (int ks = 0; ks < 2; ++ks) {
                short8 a = *(const short8*)&Ks[mt * 16 + l15][ks * 32 + quad * 8];
                c = __builtin_amdgcn_mfma_f32_16x16x32_bf16(a, Qf[ks], c, 0, 0, 0);
            }

            // fixed-shift softmax (mask <= 0, |s*scale| bounded -> fp32-safe)
            const float4 m4 = *(const float4*)(mrow + kt * 64 + mt * 16 + quad * 4);
            const float mv[4] = {m4.x, m4.y, m4.z, m4.w};
            short4v Af;
            #pragma unroll
            for (int r = 0; r < 4; ++r) {
                const float pv = exp2f(fmaf(c[r], SCALE_LOG2E, mv[r] * LOG2E));
                lst += pv;
                Af[r] = (short)f2bf(pv);
            }

            // PV: O[q][d] += P(16q x 16key) @ V(16key x 64d), K=16 MFMA.
            // A = packed P (direct from C-frag layout); B[k=key][n=d] from Vs.
            #pragma unroll
            for (int nt = 0; nt < 4; ++nt) {
                short4v Bf = *(const short4v*)&Vs[nt * 16 + l15][mt * 16 + quad * 4];
                Of[nt] = mfma16x16x16(Af, Bf, Of[nt]);
            }
        }
    }

    // ---- epilogue: reduce l across quads, normalize, store ----
    lst += __shfl_xor(lst, 16);
    lst += __shfl_xor(lst, 32);   // lane with l15=q now holds full row sum
    #pragma unroll
    for (int r = 0; r < 4; ++r) {
        const float lrow = __shfl(lst, quad * 4 + r);   // row q = quad*4+r
        const float inv  = 1.0f / lrow;
        const int s = qb * 64 + wave * 16 + quad * 4 + r;
        float* orow = out + ((size_t)s * BATCH + bb) * HID + hh * 64;
        #pragma unroll
        for (int nt = 0; nt < 4; ++nt)
            orow[nt * 16 + l15] = Of[nt][r] * inv;
    }
}

// ---------------------------------------------------------------------------
extern "C" void kernel_launch(void* const* d_in, const int* in_sizes, int n_in,
                              void* d_out, int out_size, void* d_ws, size_t ws_size,
                              hipStream_t stream) {
    const float* x    = (const float*)d_in[0];
    const float* mask = (const float*)d_in[1];
    const float* Wq   = (const float*)d_in[2];
    const float* bq   = (const float*)d_in[3];
    const float* Wk   = (const float*)d_in[4];
    const float* bk   = (const float*)d_in[5];
    const float* Wv   = (const float*)d_in[6];
    const float* bv   = (const float*)d_in[7];
    float* out = (float*)d_out;

    const size_t per = (size_t)BH * SEQ * HDIM;   // 4,194,304 elems (8 MB bf16)
    unsigned short* qw = (unsigned short*)d_ws;   // 8 MB
    unsigned short* kw = qw + per;                // 8 MB
    unsigned short* vw = kw + per;                // 8 MB (V transposed [bh][d][s])
    unsigned short* xb = vw + per;                // 8 MB (x bf16)
    unsigned short* wt = xb + per;                // 6 MB (3x W^T bf16)

    convert_x<<<dim3(SEQ * BATCH * HID / 4 / 256), dim3(256), 0, stream>>>(x, xb);
    transpose_w<<<dim3(32, 32, 3), dim3(256), 0, stream>>>(Wq, Wk, Wv, wt);

    qkv_mfma<<<dim3(HID / 128, SEQ * BATCH / 128, 3), dim3(256), 0, stream>>>(
        xb, wt, bq, bk, bv, qw);

    attn_v6<<<dim3(SEQ / 64, BH), dim3(256), 0, stream>>>(qw, kw, vw, mask, out);
}

// Round 8
// 257.647 us; speedup vs baseline: 1.2299x; 1.0172x over previous
//
#include <hip/hip_runtime.h>
#include <hip/hip_bf16.h>

// Problem constants (BertSelfAttention_979252544303)
#define SEQ   2048
#define BATCH 2
#define HID   1024
#define NHEAD 16
#define HDIM  64
#define BH    (BATCH * NHEAD)   // 32 flattened heads

using short4v  = __attribute__((ext_vector_type(4))) short;
using short8   = __attribute__((ext_vector_type(8))) short;
using floatx4  = __attribute__((ext_vector_type(4))) float;

#define LOG2E 1.44269504f
#define SCALE_LOG2E (0.125f * LOG2E)   // (1/sqrt(64)) * log2(e)

// float -> bf16 (RNE)
static __device__ __forceinline__ unsigned short f2bf(float f) {
    unsigned int u = __builtin_bit_cast(unsigned int, f);
    u += 0x7fffu + ((u >> 16) & 1u);
    return (unsigned short)(u >> 16);
}

// D = A(16x16 bf16) * B(16x16 bf16) + C  — per-wave MFMA, K=16
static __device__ __forceinline__ floatx4 mfma16x16x16(
    short4v a, short4v b, floatx4 c) {
#if __has_builtin(__builtin_amdgcn_mfma_f32_16x16x16bf16_1k)
    return __builtin_amdgcn_mfma_f32_16x16x16bf16_1k(a, b, c, 0, 0, 0);
#else
    floatx4 d;
    asm volatile("v_mfma_f32_16x16x16_bf16 %0, %1, %2, %3"
                 : "=v"(d) : "v"(a), "v"(b), "v"(c));
    return d;
#endif
}

#define GLD16(gp, lp)                                                        \
    __builtin_amdgcn_global_load_lds(                                        \
        (const __attribute__((address_space(1))) void*)(gp),                 \
        (__attribute__((address_space(3))) void*)(lp), 16, 0, 0)

// ---------------------------------------------------------------------------
// Prep 1: x fp32 [4096][1024] -> bf16 (straight). 1 float4 per thread.
// ---------------------------------------------------------------------------
__global__ __launch_bounds__(256) void convert_x(
    const float* __restrict__ x, unsigned short* __restrict__ xb)
{
    const int i = blockIdx.x * 256 + threadIdx.x;
    const float4 v = ((const float4*)x)[i];
    ushort4 o;
    o.x = f2bf(v.x); o.y = f2bf(v.y); o.z = f2bf(v.z); o.w = f2bf(v.w);
    ((ushort4*)xb)[i] = o;
}

// ---------------------------------------------------------------------------
// Prep 2: W fp32 [k][n] -> wt bf16 [n][k], tiled transpose. z selects Q/K/V.
// ---------------------------------------------------------------------------
__global__ __launch_bounds__(256) void transpose_w(
    const float* __restrict__ Wq, const float* __restrict__ Wk,
    const float* __restrict__ Wv, unsigned short* __restrict__ wt)
{
    const float* W = (blockIdx.z == 0) ? Wq : (blockIdx.z == 1) ? Wk : Wv;
    unsigned short* out = wt + (size_t)blockIdx.z * HID * HID;
    __shared__ float tile[32][33];
    const int tx = threadIdx.x & 31, ty = threadIdx.x >> 5;
    const int bx = blockIdx.x * 32, by = blockIdx.y * 32;
    #pragma unroll
    for (int j = 0; j < 4; ++j)
        tile[ty + j * 8][tx] = W[(size_t)(by + ty + j * 8) * HID + bx + tx];
    __syncthreads();
    #pragma unroll
    for (int j = 0; j < 4; ++j)
        out[(size_t)(bx + ty + j * 8) * HID + by + tx] = f2bf(tile[tx][ty + j * 8]);
}

// ---------------------------------------------------------------------------
// Kernel 1: fused QKV projection, bf16 MFMA. v2: ping-pong LDS double buffer
// with GLD16 — DMA for tile kt+1 issued BEFORE computing tile kt; ONE barrier
// per iteration (it drains the DMA issued a full compute-phase earlier).
// z: 0=Q, 1=K (out [bh][s][d]), 2=V (out [bh][d][s]).
// ---------------------------------------------------------------------------
__global__ __launch_bounds__(256) void qkv_mfma(
    const unsigned short* __restrict__ xb,
    const unsigned short* __restrict__ wt,
    const float* __restrict__ bq, const float* __restrict__ bk,
    const float* __restrict__ bv,
    unsigned short* __restrict__ ws_out)
{
    const int bn = blockIdx.x;   // 0..7
    const int bm = blockIdx.y;   // 0..31
    const int z  = blockIdx.z;   // 0..2
    const unsigned short* Bt = wt + (size_t)z * HID * HID;
    const float* bias = (z == 0) ? bq : (z == 1) ? bk : bv;
    unsigned short* out = ws_out + (size_t)z * (size_t)BH * SEQ * HDIM;

    const int t    = threadIdx.x;
    const int wave = t >> 6;
    const int lane = t & 63;
    const int l15  = lane & 15;
    const int quad = lane >> 4;
    const int wm   = (wave >> 1) * 64;
    const int wn   = (wave & 1) * 64;

    // two 8 KB buffers each for A and B
    __shared__ __align__(16) unsigned short As[2][128 * 32];
    __shared__ __align__(16) unsigned short Bs[2][128 * 32];

    floatx4 acc[4][4];
    #pragma unroll
    for (int i = 0; i < 4; ++i)
        #pragma unroll
        for (int j = 0; j < 4; ++j)
            acc[i][j] = (floatx4){0.f, 0.f, 0.f, 0.f};

    const int lrow = lane >> 2;
    const int lcol = (lane & 3) * 8;

    // stage tile kt into buffer buf (2 GLD16 for A, 2 for B per thread)
    #define QKV_STAGE(kt, buf)                                                  \
        do {                                                                    \
            _Pragma("unroll")                                                   \
            for (int ee = 0; ee < 2; ++ee) {                                    \
                const int e = wave * 2 + ee;                                    \
                const unsigned short* ga = xb +                                 \
                    (size_t)(bm * 128 + e * 16 + lrow) * HID + (kt) * 32 + lcol;\
                const unsigned short* gb = Bt +                                 \
                    (size_t)(bn * 128 + e * 16 + lrow) * HID + (kt) * 32 + lcol;\
                GLD16(ga, (char*)As[buf] + e * 1024);                           \
                GLD16(gb, (char*)Bs[buf] + e * 1024);                           \
            }                                                                   \
        } while (0)

    QKV_STAGE(0, 0);

    for (int kt = 0; kt < HID / 32; ++kt) {
        const int buf = kt & 1;
        __syncthreads();   // drains DMA for tile kt; syncs prev compute reads
        if (kt + 1 < HID / 32)
            QKV_STAGE(kt + 1, buf ^ 1);   // overlaps with compute below

        short8 af[4], bf[4];
        #pragma unroll
        for (int mt = 0; mt < 4; ++mt)
            af[mt] = *(const short8*)&As[buf][(wm + mt * 16 + l15) * 32 + quad * 8];
        #pragma unroll
        for (int nt = 0; nt < 4; ++nt)
            bf[nt] = *(const short8*)&Bs[buf][(wn + nt * 16 + l15) * 32 + quad * 8];
        #pragma unroll
        for (int mt = 0; mt < 4; ++mt)
            #pragma unroll
            for (int nt = 0; nt < 4; ++nt)
                acc[mt][nt] = __builtin_amdgcn_mfma_f32_16x16x32_bf16(
                    af[mt], bf[nt], acc[mt][nt], 0, 0, 0);
    }
    #undef QKV_STAGE

    #pragma unroll
    for (int nt = 0; nt < 4; ++nt) {
        const int n_g = bn * 128 + wn + nt * 16 + l15;
        const float bsv = bias[n_g];
        const int h = n_g >> 6;
        const int d = n_g & 63;
        #pragma unroll
        for (int mt = 0; mt < 4; ++mt) {
            #pragma unroll
            for (int r = 0; r < 4; ++r) {
                const int m_g = bm * 128 + wm + mt * 16 + quad * 4 + r;
                const int s  = m_g >> 1;
                const int bb = m_g & 1;
                const unsigned short val = f2bf(acc[mt][nt][r] + bsv);
                if (z < 2)
                    out[((size_t)(bb * NHEAD + h) * SEQ + s) * HDIM + d] = val;
                else
                    out[((size_t)(bb * NHEAD + h) * HDIM + d) * SEQ + s] = val;
            }
        }
    }
}

// ---------------------------------------------------------------------------
// Kernel 2: flash attention v7 = v6 + register-prefetch staging: K/V tile
// kt+1 is loaded into registers BEFORE computing tile kt (single LDS buffer;
// the regs->LDS write at the next iteration's top finds data arrived).
// 256 threads, 4 waves x 16 q-rows, grid (32 qb, 32 heads) = 1024 blocks.
// In-register P (S^T C-frag == 16x16x16 A-frag), fixed-shift softmax.
// q,kp: [bh][s][d] bf16; vt: [bh][d][s] bf16; mask: [B][1][S][S] fp32.
// ---------------------------------------------------------------------------
__global__ __launch_bounds__(256) void attn_v7(
    const unsigned short* __restrict__ q,
    const unsigned short* __restrict__ kp,
    const unsigned short* __restrict__ vt,
    const float* __restrict__ mask,
    float* __restrict__ out)
{
    const int qb   = blockIdx.x;   // 0..31 query tile (64 rows)
    const int n    = blockIdx.y;   // 0..31 flattened head
    const int t    = threadIdx.x;
    const int wave = t >> 6;
    const int lane = t & 63;
    const int l15  = lane & 15;
    const int quad = lane >> 4;
    const int bb   = n >> 4;       // batch
    const int hh   = n & 15;       // head

    // rows padded to 72 bf16 (144 B; b128 frag reads at min bank cost)
    __shared__ __align__(16) unsigned short Ks[64][72];   // [key][k]
    __shared__ __align__(16) unsigned short Vs[64][72];   // [d][key]

    // ---- Q fragments straight from global (one-time) ----
    const unsigned short* qbase = q + ((size_t)n * SEQ + qb * 64) * HDIM;
    short8 Qf[2];
    #pragma unroll
    for (int ks = 0; ks < 2; ++ks)
        Qf[ks] = *(const short8*)(qbase +
            (size_t)(wave * 16 + l15) * HDIM + ks * 32 + quad * 8);

    floatx4 Of[4];
    #pragma unroll
    for (int nt = 0; nt < 4; ++nt) Of[nt] = (floatx4){0.f, 0.f, 0.f, 0.f};
    float lst = 0.0f;

    const unsigned short* kbase = kp + (size_t)n * SEQ * HDIM;
    const unsigned short* vbase = vt + (size_t)n * HDIM * SEQ;
    const float* mrow = mask + ((size_t)bb * SEQ + qb * 64 + wave * 16 + l15) * SEQ;

    // per-thread staging addresses (two 8-bf16 chunks each for K and V)
    const int c0 = t,        r0 = c0 >> 3, o0 = (c0 & 7) * 8;
    const int c1 = t + 256,  r1 = c1 >> 3, o1 = (c1 & 7) * 8;

    uint4 kreg0, kreg1, vreg0, vreg1;
    {   // prefetch tile 0
        const unsigned short* kb = kbase;
        const unsigned short* vb = vbase;
        kreg0 = *(const uint4*)(kb + (size_t)r0 * HDIM + o0);
        kreg1 = *(const uint4*)(kb + (size_t)r1 * HDIM + o1);
        vreg0 = *(const uint4*)(vb + (size_t)r0 * SEQ + o0);
        vreg1 = *(const uint4*)(vb + (size_t)r1 * SEQ + o1);
    }

    for (int kt = 0; kt < SEQ / 64; ++kt) {
        __syncthreads();   // previous K/V tile fully consumed
        *(uint4*)&Ks[r0][o0] = kreg0;
        *(uint4*)&Ks[r1][o1] = kreg1;
        *(uint4*)&Vs[r0][o0] = vreg0;
        *(uint4*)&Vs[r1][o1] = vreg1;
        __syncthreads();   // tile kt visible to all waves

        if (kt + 1 < SEQ / 64) {   // prefetch kt+1 (overlaps compute below)
            const unsigned short* kb = kbase + (size_t)((kt + 1) * 64) * HDIM;
            const unsigned short* vb = vbase + (kt + 1) * 64;
            kreg0 = *(const uint4*)(kb + (size_t)r0 * HDIM + o0);
            kreg1 = *(const uint4*)(kb + (size_t)r1 * HDIM + o1);
            vreg0 = *(const uint4*)(vb + (size_t)r0 * SEQ + o0);
            vreg1 = *(const uint4*)(vb + (size_t)r1 * SEQ + o1);
        }

        // per 16-key subtile: S^T MFMA -> softmax -> in-register P -> PV
        #pragma unroll
        for (int mt = 0; mt < 4; ++mt) {
            floatx4 c = (floatx4){0.f, 0.f, 0.f, 0.f};
            #pragma unroll
            for (int ks = 0; ks < 2; ++ks) {
                short8 a = *(const short8*)&Ks[mt * 16 + l15][ks * 32 + quad * 8];
                c = __builtin_amdgcn_mfma_f32_16x16x32_bf16(a, Qf[ks], c, 0, 0, 0);
            }

            const float4 m4 = *(const float4*)(mrow + kt * 64 + mt * 16 + quad * 4);
            const float mv[4] = {m4.x, m4.y, m4.z, m4.w};
            short4v Af;
            #pragma unroll
            for (int r = 0; r < 4; ++r) {
                const float pv = exp2f(fmaf(c[r], SCALE_LOG2E, mv[r] * LOG2E));
                lst += pv;
                Af[r] = (short)f2bf(pv);
            }

            #pragma unroll
            for (int nt = 0; nt < 4; ++nt) {
                short4v Bf = *(const short4v*)&Vs[nt * 16 + l15][mt * 16 + quad * 4];
                Of[nt] = mfma16x16x16(Af, Bf, Of[nt]);
            }
        }
    }

    // ---- epilogue: reduce l across quads, normalize, store ----
    lst += __shfl_xor(lst, 16);
    lst += __shfl_xor(lst, 32);   // lane with l15=q now holds full row sum
    #pragma unroll
    for (int r = 0; r < 4; ++r) {
        const float lrow = __shfl(lst, quad * 4 + r);   // row q = quad*4+r
        const float inv  = 1.0f / lrow;
        const int s = qb * 64 + wave * 16 + quad * 4 + r;
        float* orow = out + ((size_t)s * BATCH + bb) * HID + hh * 64;
        #pragma unroll
        for (int nt = 0; nt < 4; ++nt)
            orow[nt * 16 + l15] = Of[nt][r] * inv;
    }
}

// ---------------------------------------------------------------------------
extern "C" void kernel_launch(void* const* d_in, const int* in_sizes, int n_in,
                              void* d_out, int out_size, void* d_ws, size_t ws_size,
                              hipStream_t stream) {
    const float* x    = (const float*)d_in[0];
    const float* mask = (const float*)d_in[1];
    const float* Wq   = (const float*)d_in[2];
    const float* bq   = (const float*)d_in[3];
    const float* Wk   = (const float*)d_in[4];
    const float* bk   = (const float*)d_in[5];
    const float* Wv   = (const float*)d_in[6];
    const float* bv   = (const float*)d_in[7];
    float* out = (float*)d_out;

    const size_t per = (size_t)BH * SEQ * HDIM;   // 4,194,304 elems (8 MB bf16)
    unsigned short* qw = (unsigned short*)d_ws;   // 8 MB
    unsigned short* kw = qw + per;                // 8 MB
    unsigned short* vw = kw + per;                // 8 MB (V transposed [bh][d][s])
    unsigned short* xb = vw + per;                // 8 MB (x bf16)
    unsigned short* wt = xb + per;                // 6 MB (3x W^T bf16)

    convert_x<<<dim3(SEQ * BATCH * HID / 4 / 256), dim3(256), 0, stream>>>(x, xb);
    transpose_w<<<dim3(32, 32, 3), dim3(256), 0, stream>>>(Wq, Wk, Wv, wt);

    qkv_mfma<<<dim3(HID / 128, SEQ * BATCH / 128, 3), dim3(256), 0, stream>>>(
        xb, wt, bq, bk, bv, qw);

    attn_v7<<<dim3(SEQ / 64, BH), dim3(256), 0, stream>>>(qw, kw, vw, mask, out);
}

// Round 9
// 252.887 us; speedup vs baseline: 1.2530x; 1.0188x over previous
//
#include <hip/hip_runtime.h>
#include <hip/hip_bf16.h>

// Problem constants (BertSelfAttention_979252544303)
#define SEQ   2048
#define BATCH 2
#define HID   1024
#define NHEAD 16
#define HDIM  64
#define BH    (BATCH * NHEAD)   // 32 flattened heads

using short4v  = __attribute__((ext_vector_type(4))) short;
using short8   = __attribute__((ext_vector_type(8))) short;
using floatx4  = __attribute__((ext_vector_type(4))) float;

#define LOG2E 1.44269504f
#define SCALE_LOG2E (0.125f * LOG2E)   // (1/sqrt(64)) * log2(e)

// attn LDS row pitch in bf16 elems: 80 (= 40 dwords) so staging-write banks
// (8r+4c) mod 32 are 2-way max (free); 72 gave 4(r+c) mod 32 = 8-way.
#define KVP 80

// float -> bf16 (RNE)
static __device__ __forceinline__ unsigned short f2bf(float f) {
    unsigned int u = __builtin_bit_cast(unsigned int, f);
    u += 0x7fffu + ((u >> 16) & 1u);
    return (unsigned short)(u >> 16);
}

// D = A(16x16 bf16) * B(16x16 bf16) + C  — per-wave MFMA, K=16
static __device__ __forceinline__ floatx4 mfma16x16x16(
    short4v a, short4v b, floatx4 c) {
#if __has_builtin(__builtin_amdgcn_mfma_f32_16x16x16bf16_1k)
    return __builtin_amdgcn_mfma_f32_16x16x16bf16_1k(a, b, c, 0, 0, 0);
#else
    floatx4 d;
    asm volatile("v_mfma_f32_16x16x16_bf16 %0, %1, %2, %3"
                 : "=v"(d) : "v"(a), "v"(b), "v"(c));
    return d;
#endif
}

#define GLD16(gp, lp)                                                        \
    __builtin_amdgcn_global_load_lds(                                        \
        (const __attribute__((address_space(1))) void*)(gp),                 \
        (__attribute__((address_space(3))) void*)(lp), 16, 0, 0)

// ---------------------------------------------------------------------------
// Prep 1: x fp32 [4096][1024] -> bf16 (straight). 1 float4 per thread.
// ---------------------------------------------------------------------------
__global__ __launch_bounds__(256) void convert_x(
    const float* __restrict__ x, unsigned short* __restrict__ xb)
{
    const int i = blockIdx.x * 256 + threadIdx.x;
    const float4 v = ((const float4*)x)[i];
    ushort4 o;
    o.x = f2bf(v.x); o.y = f2bf(v.y); o.z = f2bf(v.z); o.w = f2bf(v.w);
    ((ushort4*)xb)[i] = o;
}

// ---------------------------------------------------------------------------
// Prep 2: W fp32 [k][n] -> wt bf16 [n][k], tiled transpose. z selects Q/K/V.
// ---------------------------------------------------------------------------
__global__ __launch_bounds__(256) void transpose_w(
    const float* __restrict__ Wq, const float* __restrict__ Wk,
    const float* __restrict__ Wv, unsigned short* __restrict__ wt)
{
    const float* W = (blockIdx.z == 0) ? Wq : (blockIdx.z == 1) ? Wk : Wv;
    unsigned short* out = wt + (size_t)blockIdx.z * HID * HID;
    __shared__ float tile[32][33];
    const int tx = threadIdx.x & 31, ty = threadIdx.x >> 5;
    const int bx = blockIdx.x * 32, by = blockIdx.y * 32;
    #pragma unroll
    for (int j = 0; j < 4; ++j)
        tile[ty + j * 8][tx] = W[(size_t)(by + ty + j * 8) * HID + bx + tx];
    __syncthreads();
    #pragma unroll
    for (int j = 0; j < 4; ++j)
        out[(size_t)(bx + ty + j * 8) * HID + by + tx] = f2bf(tile[tx][ty + j * 8]);
}

// ---------------------------------------------------------------------------
// Kernel 1: fused QKV projection, bf16 MFMA, GLD16 ping-pong dbuf.
// z: 0=Q, 1=K (out [bh][s][d]) use direct scalar epilogue (d-contiguous,
// OK coalescing). z=2 (V, out [bh][d][s]) uses an LDS-bounce epilogue:
// the direct path was a 2-byte scatter at 4 KB stride (64 partial-line
// stores/wave); the bounce emits only full-128B-line dwordx4 stores.
// Shared LDS union: loop uses As/Bs dbuf (32 KB), epilogue reuses it as a
// 128x136 C tile (34.8 KB alloc; grid-bound at 3 blocks/CU regardless).
// ---------------------------------------------------------------------------
#define CTP 136   // C-tile pitch: 128 + 8 pad
__global__ __launch_bounds__(256) void qkv_mfma(
    const unsigned short* __restrict__ xb,
    const unsigned short* __restrict__ wt,
    const float* __restrict__ bq, const float* __restrict__ bk,
    const float* __restrict__ bv,
    unsigned short* __restrict__ ws_out)
{
    const int bn = blockIdx.x;   // 0..7
    const int bm = blockIdx.y;   // 0..31
    const int z  = blockIdx.z;   // 0..2
    const unsigned short* Bt = wt + (size_t)z * HID * HID;
    const float* bias = (z == 0) ? bq : (z == 1) ? bk : bv;
    unsigned short* out = ws_out + (size_t)z * (size_t)BH * SEQ * HDIM;

    const int t    = threadIdx.x;
    const int wave = t >> 6;
    const int lane = t & 63;
    const int l15  = lane & 15;
    const int quad = lane >> 4;
    const int wm   = (wave >> 1) * 64;
    const int wn   = (wave & 1) * 64;

    // union: [0,16384) = As dbuf + Bs dbuf (4x 4096 elems); epilogue C tile
    // needs 128*CTP = 17408 elems.
    __shared__ __align__(16) unsigned short smem[128 * CTP];
    #define ASB(buf) (smem + (buf) * 4096)
    #define BSB(buf) (smem + 8192 + (buf) * 4096)

    floatx4 acc[4][4];
    #pragma unroll
    for (int i = 0; i < 4; ++i)
        #pragma unroll
        for (int j = 0; j < 4; ++j)
            acc[i][j] = (floatx4){0.f, 0.f, 0.f, 0.f};

    const int lrow = lane >> 2;
    const int lcol = (lane & 3) * 8;

    #define QKV_STAGE(kt, buf)                                                  \
        do {                                                                    \
            _Pragma("unroll")                                                   \
            for (int ee = 0; ee < 2; ++ee) {                                    \
                const int e = wave * 2 + ee;                                    \
                const unsigned short* ga = xb +                                 \
                    (size_t)(bm * 128 + e * 16 + lrow) * HID + (kt) * 32 + lcol;\
                const unsigned short* gb = Bt +                                 \
                    (size_t)(bn * 128 + e * 16 + lrow) * HID + (kt) * 32 + lcol;\
                GLD16(ga, (char*)ASB(buf) + e * 1024);                          \
                GLD16(gb, (char*)BSB(buf) + e * 1024);                          \
            }                                                                   \
        } while (0)

    QKV_STAGE(0, 0);

    for (int kt = 0; kt < HID / 32; ++kt) {
        const int buf = kt & 1;
        __syncthreads();   // drains DMA for tile kt; syncs prev compute reads
        if (kt + 1 < HID / 32)
            QKV_STAGE(kt + 1, buf ^ 1);   // overlaps with compute below

        short8 af[4], bf[4];
        #pragma unroll
        for (int mt = 0; mt < 4; ++mt)
            af[mt] = *(const short8*)&ASB(buf)[(wm + mt * 16 + l15) * 32 + quad * 8];
        #pragma unroll
        for (int nt = 0; nt < 4; ++nt)
            bf[nt] = *(const short8*)&BSB(buf)[(wn + nt * 16 + l15) * 32 + quad * 8];
        #pragma unroll
        for (int mt = 0; mt < 4; ++mt)
            #pragma unroll
            for (int nt = 0; nt < 4; ++nt)
                acc[mt][nt] = __builtin_amdgcn_mfma_f32_16x16x32_bf16(
                    af[mt], bf[nt], acc[mt][nt], 0, 0, 0);
    }
    #undef QKV_STAGE

    if (z < 2) {
        #pragma unroll
        for (int nt = 0; nt < 4; ++nt) {
            const int n_g = bn * 128 + wn + nt * 16 + l15;
            const float bsv = bias[n_g];
            const int h = n_g >> 6;
            const int d = n_g & 63;
            #pragma unroll
            for (int mt = 0; mt < 4; ++mt) {
                #pragma unroll
                for (int r = 0; r < 4; ++r) {
                    const int m_g = bm * 128 + wm + mt * 16 + quad * 4 + r;
                    const int s  = m_g >> 1;
                    const int bb = m_g & 1;
                    out[((size_t)(bb * NHEAD + h) * SEQ + s) * HDIM + d] =
                        f2bf(acc[mt][nt][r] + bsv);
                }
            }
        }
    } else {
        // ---- V: LDS bounce -> coalesced [bh][d][s] stores ----
        __syncthreads();   // all frag reads from As/Bs complete before reuse
        #pragma unroll
        for (int nt = 0; nt < 4; ++nt) {
            const int n_l = wn + nt * 16 + l15;
            const float bsv = bias[bn * 128 + n_l];
            #pragma unroll
            for (int mt = 0; mt < 4; ++mt) {
                #pragma unroll
                for (int r = 0; r < 4; ++r) {
                    const int m_l = wm + mt * 16 + quad * 4 + r;
                    // m -> (s_l, bb): s interleaved with batch (BATCH==2)
                    smem[n_l * CTP + (m_l & 1) * 64 + (m_l >> 1)] =
                        f2bf(acc[mt][nt][r] + bsv);
                }
            }
        }
        __syncthreads();
        // read back: thread t owns row (n_l = t>>1, bb = t&1) = 64 s * 2B
        const int n_l = t >> 1;
        const int b2  = t & 1;
        const int n_g = bn * 128 + n_l;
        const int h   = n_g >> 6;
        const int d   = n_g & 63;
        const unsigned short* src = smem + n_l * CTP + b2 * 64;
        unsigned short* dst =
            out + ((size_t)(b2 * NHEAD + h) * HDIM + d) * SEQ + bm * 64;
        #pragma unroll
        for (int c = 0; c < 8; ++c)    // 8 x 16B = 128 B (one full line set)
            *(uint4*)(dst + c * 8) = *(const uint4*)(src + c * 8);
    }
}
#undef CTP

// ---------------------------------------------------------------------------
// Kernel 2: flash attention v8 = v7 with LDS pitch 72 -> 80 (kills the 8-way
// staging-write bank conflicts; reads stay at ideal cycles).
// 256 threads, 4 waves x 16 q-rows, grid (32 qb, 32 heads) = 1024 blocks.
// Register-prefetch staging (tile kt+1 loaded during compute of kt).
// In-register P (S^T C-frag == 16x16x16 A-frag), fixed-shift softmax.
// q,kp: [bh][s][d] bf16; vt: [bh][d][s] bf16; mask: [B][1][S][S] fp32.
// ---------------------------------------------------------------------------
__global__ __launch_bounds__(256) void attn_v8(
    const unsigned short* __restrict__ q,
    const unsigned short* __restrict__ kp,
    const unsigned short* __restrict__ vt,
    const float* __restrict__ mask,
    float* __restrict__ out)
{
    const int qb   = blockIdx.x;   // 0..31 query tile (64 rows)
    const int n    = blockIdx.y;   // 0..31 flattened head
    const int t    = threadIdx.x;
    const int wave = t >> 6;
    const int lane = t & 63;
    const int l15  = lane & 15;
    const int quad = lane >> 4;
    const int bb   = n >> 4;       // batch
    const int hh   = n & 15;       // head

    __shared__ __align__(16) unsigned short Ks[64][KVP];   // [key][k]
    __shared__ __align__(16) unsigned short Vs[64][KVP];   // [d][key]

    // ---- Q fragments straight from global (one-time) ----
    const unsigned short* qbase = q + ((size_t)n * SEQ + qb * 64) * HDIM;
    short8 Qf[2];
    #pragma unroll
    for (int ks = 0; ks < 2; ++ks)
        Qf[ks] = *(const short8*)(qbase +
            (size_t)(wave * 16 + l15) * HDIM + ks * 32 + quad * 8);

    floatx4 Of[4];
    #pragma unroll
    for (int nt = 0; nt < 4; ++nt) Of[nt] = (floatx4){0.f, 0.f, 0.f, 0.f};
    float lst = 0.0f;

    const unsigned short* kbase = kp + (size_t)n * SEQ * HDIM;
    const unsigned short* vbase = vt + (size_t)n * HDIM * SEQ;
    const float* mrow = mask + ((size_t)bb * SEQ + qb * 64 + wave * 16 + l15) * SEQ;

    // per-thread staging addresses (two 8-bf16 chunks each for K and V)
    const int c0 = t,        r0 = c0 >> 3, o0 = (c0 & 7) * 8;
    const int c1 = t + 256,  r1 = c1 >> 3, o1 = (c1 & 7) * 8;

    uint4 kreg0, kreg1, vreg0, vreg1;
    {   // prefetch tile 0
        kreg0 = *(const uint4*)(kbase + (size_t)r0 * HDIM + o0);
        kreg1 = *(const uint4*)(kbase + (size_t)r1 * HDIM + o1);
        vreg0 = *(const uint4*)(vbase + (size_t)r0 * SEQ + o0);
        vreg1 = *(const uint4*)(vbase + (size_t)r1 * SEQ + o1);
    }

    for (int kt = 0; kt < SEQ / 64; ++kt) {
        __syncthreads();   // previous K/V tile fully consumed
        *(uint4*)&Ks[r0][o0] = kreg0;
        *(uint4*)&Ks[r1][o1] = kreg1;
        *(uint4*)&Vs[r0][o0] = vreg0;
        *(uint4*)&Vs[r1][o1] = vreg1;
        __syncthreads();   // tile kt visible to all waves

        if (kt + 1 < SEQ / 64) {   // prefetch kt+1 (overlaps compute below)
            const unsigned short* kb = kbase + (size_t)((kt + 1) * 64) * HDIM;
            const unsigned short* vb = vbase + (kt + 1) * 64;
            kreg0 = *(const uint4*)(kb + (size_t)r0 * HDIM + o0);
            kreg1 = *(const uint4*)(kb + (size_t)r1 * HDIM + o1);
            vreg0 = *(const uint4*)(vb + (size_t)r0 * SEQ + o0);
            vreg1 = *(const uint4*)(vb + (size_t)r1 * SEQ + o1);
        }

        // per 16-key subtile: S^T MFMA -> softmax -> in-register P -> PV
        #pragma unroll
        for (int mt = 0; mt < 4; ++mt) {
            floatx4 c = (floatx4){0.f, 0.f, 0.f, 0.f};
            #pragma unroll
            for (int ks = 0; ks < 2; ++ks) {
                short8 a = *(const short8*)&Ks[mt * 16 + l15][ks * 32 + quad * 8];
                c = __builtin_amdgcn_mfma_f32_16x16x32_bf16(a, Qf[ks], c, 0, 0, 0);
            }

            const float4 m4 = *(const float4*)(mrow + kt * 64 + mt * 16 + quad * 4);
            const float mv[4] = {m4.x, m4.y, m4.z, m4.w};
            short4v Af;
            #pragma unroll
            for (int r = 0; r < 4; ++r) {
                const float pv = exp2f(fmaf(c[r], SCALE_LOG2E, mv[r] * LOG2E));
                lst += pv;
                Af[r] = (short)f2bf(pv);
            }

            #pragma unroll
            for (int nt = 0; nt < 4; ++nt) {
                short4v Bf = *(const short4v*)&Vs[nt * 16 + l15][mt * 16 + quad * 4];
                Of[nt] = mfma16x16x16(Af, Bf, Of[nt]);
            }
        }
    }

    // ---- epilogue: reduce l across quads, normalize, store ----
    lst += __shfl_xor(lst, 16);
    lst += __shfl_xor(lst, 32);   // lane with l15=q now holds full row sum
    #pragma unroll
    for (int r = 0; r < 4; ++r) {
        const float lrow = __shfl(lst, quad * 4 + r);   // row q = quad*4+r
        const float inv  = 1.0f / lrow;
        const int s = qb * 64 + wave * 16 + quad * 4 + r;
        float* orow = out + ((size_t)s * BATCH + bb) * HID + hh * 64;
        #pragma unroll
        for (int nt = 0; nt < 4; ++nt)
            orow[nt * 16 + l15] = Of[nt][r] * inv;
    }
}

// ---------------------------------------------------------------------------
extern "C" void kernel_launch(void* const* d_in, const int* in_sizes, int n_in,
                              void* d_out, int out_size, void* d_ws, size_t ws_size,
                              hipStream_t stream) {
    const float* x    = (const float*)d_in[0];
    const float* mask = (const float*)d_in[1];
    const float* Wq   = (const float*)d_in[2];
    const float* bq   = (const float*)d_in[3];
    const float* Wk   = (const float*)d_in[4];
    const float* bk   = (const float*)d_in[5];
    const float* Wv   = (const float*)d_in[6];
    const float* bv   = (const float*)d_in[7];
    float* out = (float*)d_out;

    const size_t per = (size_t)BH * SEQ * HDIM;   // 4,194,304 elems (8 MB bf16)
    unsigned short* qw = (unsigned short*)d_ws;   // 8 MB
    unsigned short* kw = qw + per;                // 8 MB
    unsigned short* vw = kw + per;                // 8 MB (V transposed [bh][d][s])
    unsigned short* xb = vw + per;                // 8 MB (x bf16)
    unsigned short* wt = xb + per;                // 6 MB (3x W^T bf16)

    convert_x<<<dim3(SEQ * BATCH * HID / 4 / 256), dim3(256), 0, stream>>>(x, xb);
    transpose_w<<<dim3(32, 32, 3), dim3(256), 0, stream>>>(Wq, Wk, Wv, wt);

    qkv_mfma<<<dim3(HID / 128, SEQ * BATCH / 128, 3), dim3(256), 0, stream>>>(
        xb, wt, bq, bk, bv, qw);

    attn_v8<<<dim3(SEQ / 64, BH), dim3(256), 0, stream>>>(qw, kw, vw, mask, out);
}